// Round 2
// 545.490 us; speedup vs baseline: 1.2482x; 1.2482x over previous
//
#include <hip/hip_runtime.h>
#include <stdint.h>

// out[n] = features[n] @ W[inds[n]] + b[inds[n]],  N=1M, D=64, E=8, fp32.
//
// Design: block = 512 threads = 8 waves, wave w owns expert w.
//  - lane j of wave w holds column j of W[w] in 64 VGPRs (loaded once).
//  - each wave scans the block's token chunk: 1 coalesced inds load + __ballot
//    per 64 tokens -> 64-bit match mask, walked with scalar bit ops (uniform).
//  - per matching token: feature row (256 B, wave-uniform address) loaded into
//    64 SGPRs via s_load_dwordx16. Inner loop = 64 v_fmac_f32 with SGPR src.
//  - Round 0->1: the s_load was hitting cold HBM (~900 cyc exposed per
//    token, lgkmcnt(0) is mandatory since SMEM returns out-of-order) ->
//    latency-bound at 1.4 TB/s. Each wave now prefetches its 8-row slice of
//    the group TWO groups ahead via 2 compiler-visible global_load_dwordx4
//    into throwaway VGPRs (kept alive by empty asm, consumed 2 iterations
//    later so the vmcnt wait is free). 8 waves x 8 rows = full 64-row group
//    warmed in L2 -> per-token s_load latency drops to ~200 cyc, coverable by
//    ~4 waves/SIMD. inds loads are software-pipelined one group ahead for the
//    same reason.
//  - Round 1 was a broker timeout (no bench ran); identical resubmit.

typedef float v16f __attribute__((ext_vector_type(16)));
typedef float v4f  __attribute__((ext_vector_type(4)));

constexpr int D = 64;
constexpr int CHUNK = 512;   // tokens per block; N=1048576 -> grid=2048

__global__ __launch_bounds__(512, 4)
void moe_split_kernel(const float* __restrict__ features,
                      const int* __restrict__ inds,
                      const float* __restrict__ W,
                      const float* __restrict__ b,
                      float* __restrict__ out, int N) {
    const int w    = threadIdx.x >> 6;   // wave id == expert id
    const int lane = threadIdx.x & 63;   // output column j

    // W[w][k][lane] for k=0..63 -> 64 VGPRs (coalesced 256B loads, L2/L3-hot)
    float wreg[D];
    const float* Wp = W + (size_t)w * D * D + lane;
    #pragma unroll
    for (int k = 0; k < D; ++k) wreg[k] = Wp[k * D];
    const float breg = b[w * D + lane];

    const int base = blockIdx.x * CHUNK;
    const int end  = min(base + CHUNK, N);

    // L2-prefetch state: wave w owns rows [g + 8w, g + 8w + 8) of each group g
    // (2 KB = 2 x 64 lanes x 16 B). Values are never used; empty asm keeps the
    // loads alive. Loads are compiler-visible so vmcnt bookkeeping stays exact.
    const int sliceOff = w * 8;
    v4f pa0{}, pa1{}, pb0{}, pb1{};

    auto issue_pf = [&](int g, v4f& c0, v4f& c1) {
        if (g < end && g + 64 <= N) {
            const float* pb = features + (size_t)(g + sliceOff) * D;
            c0 = *reinterpret_cast<const v4f*>(pb + lane * 4);
            c1 = *reinterpret_cast<const v4f*>(pb + 256 + lane * 4);
        }
    };

    // prologue: warm groups 0 and 1; pipeline inds for group 0
    issue_pf(base, pa0, pa1);
    issue_pf(base + 64, pb0, pb1);
    const int t0 = base + lane;
    int iv = (t0 < N) ? inds[t0] : -1;

    auto do_group = [&](int nb, v4f& c0, v4f& c1) {
        // consume the 2-groups-old prefetch (its latency long since elapsed),
        // then reissue the buffer for group nb+128.
        asm volatile("" :: "v"(c0), "v"(c1));
        issue_pf(nb + 128, c0, c1);

        // software-pipelined inds load for the next group
        const int tn = nb + 64 + lane;
        const int ivn = (nb + 64 < end && tn < N) ? inds[tn] : -1;

        unsigned long long mask = __ballot(iv == w);
        while (mask) {
            const int i = __builtin_ctzll(mask);
            mask &= mask - 1;
            const int n = nb + i;                       // wave-uniform
            const float* fp = features + (size_t)n * D; // uniform -> SGPR pair

            v16f x0, x1, x2, x3;
            asm volatile(
                "s_load_dwordx16 %0, %4, 0x0\n\t"
                "s_load_dwordx16 %1, %4, 0x40\n\t"
                "s_load_dwordx16 %2, %4, 0x80\n\t"
                "s_load_dwordx16 %3, %4, 0xc0\n\t"
                "s_waitcnt lgkmcnt(0)"
                : "=&s"(x0), "=&s"(x1), "=&s"(x2), "=&s"(x3)
                : "s"(fp));

            float acc0 = breg, acc1 = 0.0f;   // 2 chains to cover fma latency
            #pragma unroll
            for (int k = 0; k < 16; ++k) {
                acc0 = __builtin_fmaf(x0[k], wreg[k],      acc0);
                acc1 = __builtin_fmaf(x1[k], wreg[16 + k], acc1);
            }
            #pragma unroll
            for (int k = 0; k < 16; ++k) {
                acc0 = __builtin_fmaf(x2[k], wreg[32 + k], acc0);
                acc1 = __builtin_fmaf(x3[k], wreg[48 + k], acc1);
            }
            out[(size_t)n * D + lane] = acc0 + acc1;    // coalesced 256B store
        }
        iv = ivn;
    };

    for (int nb = base; nb < end; nb += 128) {
        do_group(nb, pa0, pa1);
        if (nb + 64 < end) do_group(nb + 64, pb0, pb1);
    }
}

extern "C" void kernel_launch(void* const* d_in, const int* in_sizes, int n_in,
                              void* d_out, int out_size, void* d_ws, size_t ws_size,
                              hipStream_t stream) {
    const float* features = (const float*)d_in[0];
    const int*   inds     = (const int*)d_in[1];
    const float* W        = (const float*)d_in[2];
    const float* b        = (const float*)d_in[3];
    float*       out      = (float*)d_out;

    const int N = in_sizes[0] / D;       // 1048576
    const int grid = (N + CHUNK - 1) / CHUNK;
    moe_split_kernel<<<grid, 512, 0, stream>>>(features, inds, W, b, out, N);
}